// Round 1
// baseline (385.401 us; speedup 1.0000x reference)
//
#include <hip/hip_runtime.h>

// Problem: MSE between pred_iou[32,8] and binary-Jaccard IoU computed from
// pred_masks[32,8,512,512] (fp32, threshold 0.5) vs target_masks[32,512,512]
// (int32, >0), broadcast over n. Output: squared error [32,8] fp32.
//
// Memory-bound: 256 MB pred + 32 MB target = 288 MB min traffic -> ~46 us at
// 6.3 TB/s. Each block covers ALL 8 n's for one (b, chunk) so target is read
// exactly once from HBM.

#define BS      32
#define NMASKS  8
#define HW      (512 * 512)          // 262144 elements per mask
#define CHUNKS  64                   // chunks per batch image
#define BLOCK   256
#define CHUNK_ELEMS (HW / CHUNKS)    // 4096
#define VEC_ITERS   (CHUNK_ELEMS / (BLOCK * 4))  // 4 float4-iters per thread

__global__ __launch_bounds__(BLOCK) void iou_count_kernel(
    const int* __restrict__ tgt,
    const float* __restrict__ pred,
    unsigned long long* __restrict__ ws)
{
    const int b     = blockIdx.x / CHUNKS;   // pow2 divide, cheap
    const int chunk = blockIdx.x % CHUNKS;
    const int tid   = threadIdx.x;

    const size_t tgt_base  = (size_t)b * HW + (size_t)chunk * CHUNK_ELEMS;
    const size_t pred_base = (size_t)b * NMASKS * HW + (size_t)chunk * CHUNK_ELEMS;

    unsigned int inter[NMASKS];
    unsigned int uni[NMASKS];
#pragma unroll
    for (int n = 0; n < NMASKS; ++n) { inter[n] = 0u; uni[n] = 0u; }

#pragma unroll
    for (int it = 0; it < VEC_ITERS; ++it) {
        const size_t off = (size_t)it * (BLOCK * 4) + (size_t)tid * 4;

        // target chunk: read once per block, shared across all 8 n's
        const int4 t4 = *(const int4*)(tgt + tgt_base + off);
        const int tb0 = t4.x > 0, tb1 = t4.y > 0, tb2 = t4.z > 0, tb3 = t4.w > 0;

        // issue all 8 pred streams first for ILP / outstanding loads
        float4 p[NMASKS];
#pragma unroll
        for (int n = 0; n < NMASKS; ++n)
            p[n] = *(const float4*)(pred + pred_base + (size_t)n * HW + off);

#pragma unroll
        for (int n = 0; n < NMASKS; ++n) {
            const int pb0 = p[n].x > 0.5f;
            const int pb1 = p[n].y > 0.5f;
            const int pb2 = p[n].z > 0.5f;
            const int pb3 = p[n].w > 0.5f;
            inter[n] += (unsigned)((pb0 & tb0) + (pb1 & tb1) + (pb2 & tb2) + (pb3 & tb3));
            uni[n]   += (unsigned)((pb0 | tb0) + (pb1 | tb1) + (pb2 | tb2) + (pb3 | tb3));
        }
    }

    // ---- reduction: pack (inter, union) into one u64; counts per pair
    // max 262144 so no cross-field carry ----
    const int lane = tid & 63;
    const int wave = tid >> 6;
    __shared__ unsigned long long s[BLOCK / 64][NMASKS];

#pragma unroll
    for (int n = 0; n < NMASKS; ++n) {
        unsigned long long v =
            ((unsigned long long)inter[n] << 32) | (unsigned long long)uni[n];
#pragma unroll
        for (int off = 32; off > 0; off >>= 1)
            v += __shfl_down(v, off);
        if (lane == 0) s[wave][n] = v;
    }
    __syncthreads();

    if (tid < NMASKS) {
        unsigned long long v = s[0][tid] + s[1][tid] + s[2][tid] + s[3][tid];
        atomicAdd(&ws[(size_t)b * NMASKS + tid], v);
    }
}

__global__ void finalize_kernel(const float* __restrict__ pred_iou,
                                const unsigned long long* __restrict__ ws,
                                float* __restrict__ out)
{
    const int i = threadIdx.x + blockIdx.x * blockDim.x;
    if (i < BS * NMASKS) {
        const unsigned long long v = ws[i];
        const unsigned int inter = (unsigned int)(v >> 32);
        const unsigned int uni   = (unsigned int)(v & 0xffffffffu);
        // reference: where(union>0, inter/max(union,1), 0); union>=1 when >0
        const float iou = (uni > 0u) ? ((float)inter / (float)uni) : 0.0f;
        const float d = pred_iou[i] - iou;
        out[i] = d * d;
    }
}

extern "C" void kernel_launch(void* const* d_in, const int* in_sizes, int n_in,
                              void* d_out, int out_size, void* d_ws, size_t ws_size,
                              hipStream_t stream) {
    const float* pred_iou = (const float*)d_in[0];          // [32,8]
    const int*   tgt      = (const int*)d_in[1];            // [32,512,512]
    const float* pred     = (const float*)d_in[2];          // [32,8,512,512]
    float* out = (float*)d_out;
    unsigned long long* ws = (unsigned long long*)d_ws;

    // d_ws is poisoned to 0xAA before every timed launch; zero the 2 KB of
    // counters (hipMemsetAsync is graph-capturable).
    hipMemsetAsync(d_ws, 0, (size_t)BS * NMASKS * sizeof(unsigned long long), stream);

    iou_count_kernel<<<BS * CHUNKS, BLOCK, 0, stream>>>(tgt, pred, ws);
    finalize_kernel<<<1, BLOCK, 0, stream>>>(pred_iou, ws, out);
}

// Round 3
// 358.603 us; speedup vs baseline: 1.0747x; 1.0747x over previous
//
#include <hip/hip_runtime.h>

// MSE between pred_iou[32,8] and binary-Jaccard IoU from pred_masks
// [32,8,512,512] fp32 (>0.5) vs target_masks [32,512,512] int32 (>0),
// broadcast over n. Output: squared error [32,8] fp32.
//
// Memory-bound: 256 MB pred + 32 MB target read exactly once = 288 MB ->
// ~46 us floor at 6.3 TB/s. Each block covers ALL 8 n's for one (b,chunk)
// so target is fetched once. R3 = R2 with ext_vector_type payloads so
// __builtin_nontemporal_load compiles (HIP_vector_type structs rejected).

#define BS      32
#define NMASKS  8
#define HW      (512 * 512)          // 262144 elements per mask
#define CHUNKS  64                   // chunks per batch image
#define BLOCK   256
#define NPAIRS  (BS * NMASKS)        // 256
#define CHUNK_ELEMS (HW / CHUNKS)    // 4096
#define VEC_ITERS   (CHUNK_ELEMS / (BLOCK * 4))  // 4 vec4-iters per thread

typedef int   iv4 __attribute__((ext_vector_type(4)));
typedef float fv4 __attribute__((ext_vector_type(4)));

__global__ __launch_bounds__(BLOCK) void iou_count_kernel(
    const int* __restrict__ tgt,
    const float* __restrict__ pred,
    unsigned long long* __restrict__ ws)
{
    const int b     = blockIdx.x >> 6;        // / CHUNKS
    const int chunk = blockIdx.x & (CHUNKS - 1);
    const int tid   = threadIdx.x;

    const size_t tgt_base  = (size_t)b * HW + (size_t)chunk * CHUNK_ELEMS;
    const size_t pred_base = (size_t)b * NMASKS * HW + (size_t)chunk * CHUNK_ELEMS;

    unsigned int inter[NMASKS];
    unsigned int uni[NMASKS];
#pragma unroll
    for (int n = 0; n < NMASKS; ++n) { inter[n] = 0u; uni[n] = 0u; }

#pragma unroll
    for (int it = 0; it < VEC_ITERS; ++it) {
        const size_t off = (size_t)it * (BLOCK * 4) + (size_t)tid * 4;

        // target chunk: read once per block, shared (in-register) by all 8 n's
        const iv4 t4 = __builtin_nontemporal_load((const iv4*)(tgt + tgt_base + off));
        const int tb0 = t4.x > 0, tb1 = t4.y > 0, tb2 = t4.z > 0, tb3 = t4.w > 0;

        // issue all 8 pred streams up front for MLP
        fv4 p[NMASKS];
#pragma unroll
        for (int n = 0; n < NMASKS; ++n)
            p[n] = __builtin_nontemporal_load(
                (const fv4*)(pred + pred_base + (size_t)n * HW + off));

#pragma unroll
        for (int n = 0; n < NMASKS; ++n) {
            const int pb0 = p[n].x > 0.5f;
            const int pb1 = p[n].y > 0.5f;
            const int pb2 = p[n].z > 0.5f;
            const int pb3 = p[n].w > 0.5f;
            inter[n] += (unsigned)((pb0 & tb0) + (pb1 & tb1) + (pb2 & tb2) + (pb3 & tb3));
            uni[n]   += (unsigned)((pb0 | tb0) + (pb1 | tb1) + (pb2 | tb2) + (pb3 | tb3));
        }
    }

    // ---- reduce: pack (inter,union) into one u64 (counts <= 262144, no
    // cross-field carry), wave shuffle + LDS across the 4 waves ----
    const int lane = tid & 63;
    const int wave = tid >> 6;
    __shared__ unsigned long long s[BLOCK / 64][NMASKS];

#pragma unroll
    for (int n = 0; n < NMASKS; ++n) {
        unsigned long long v =
            ((unsigned long long)inter[n] << 32) | (unsigned long long)uni[n];
#pragma unroll
        for (int off = 32; off > 0; off >>= 1)
            v += __shfl_down(v, off);
        if (lane == 0) s[wave][n] = v;
    }
    __syncthreads();

    // per-block partial -> ws[chunk][b*8+n]; every slot written exactly once,
    // so no zeroing needed and poisoned ws never leaks through.
    if (tid < NMASKS) {
        unsigned long long v = s[0][tid] + s[1][tid] + s[2][tid] + s[3][tid];
        ws[(size_t)chunk * NPAIRS + (size_t)b * NMASKS + tid] = v;
    }
}

__global__ __launch_bounds__(NPAIRS) void finalize_kernel(
    const float* __restrict__ pred_iou,
    const unsigned long long* __restrict__ ws,
    float* __restrict__ out)
{
    const int i = threadIdx.x;   // pair index 0..255; coalesced across chunks
    unsigned long long v = 0ull;
#pragma unroll
    for (int c = 0; c < CHUNKS; ++c)
        v += ws[(size_t)c * NPAIRS + i];

    const unsigned int inter = (unsigned int)(v >> 32);
    const unsigned int uni   = (unsigned int)(v & 0xffffffffu);
    // reference: where(union>0, inter/max(union,1), 0); union>=1 when >0
    const float iou = (uni > 0u) ? ((float)inter / (float)uni) : 0.0f;
    const float d = pred_iou[i] - iou;
    out[i] = d * d;
}

extern "C" void kernel_launch(void* const* d_in, const int* in_sizes, int n_in,
                              void* d_out, int out_size, void* d_ws, size_t ws_size,
                              hipStream_t stream) {
    const float* pred_iou = (const float*)d_in[0];          // [32,8]
    const int*   tgt      = (const int*)d_in[1];            // [32,512,512]
    const float* pred     = (const float*)d_in[2];          // [32,8,512,512]
    float* out = (float*)d_out;
    unsigned long long* ws = (unsigned long long*)d_ws;     // 64*256 u64 = 128 KB

    iou_count_kernel<<<BS * CHUNKS, BLOCK, 0, stream>>>(tgt, pred, ws);
    finalize_kernel<<<1, NPAIRS, 0, stream>>>(pred_iou, ws, out);
}